// Round 1
// baseline (55.450 us; speedup 1.0000x reference)
//
#include <hip/hip_runtime.h>
#include <math.h>

// Quanvolutional layer, closed form.
//
// In the CNOT-relabeled frame (R1, verified), the circuit is
//   U = prod_k [ cos(th_k/2) I - i sin(th_k/2) X_{v_k} ],  X_v|j> = |j^v>,
// measured with Z_m, m = 0x88. All X_v commute and are diagonal in the
// Walsh-Hadamard basis (eigenvalue (-1)^{w.v}); |0..0> is uniform there, so
//   E = (1/256) sum_w cos( sum_{k in S} eps_k(w) th_k ),
//   S = {k : parity(v_k & m) = 1},  eps_k(w) = (-1)^{popc(w & v_k)}.
//
// Surviving gates: 18 weight gates + 2 data gates (embed q0: v=0x80,
// th0 = x[b,0,2ph,2pw]; embed q4: v=0x08, th4 = x[b,1,2ph,2pw]).
// Expanding the data angles:
//   E = Kcc cos0 cos4 + Kss sin0 sin4 + Ksc sin0 cos4 + Kcs cos0 sin4
// with per-oc coefficients (eps0 = bit7 of w, eps4 = bit3 of w).
//
// R5 (this round): factor eps_k(w) = eps_lo(lane, v&0x3F) * eps_hi(j, v>>6)
// for w = lane + 64*j. Group the 18 gates by v>>6 into partial sums
// A0..A3; the four per-lane angles are then
//   a_j = A0 + s6 A1 + s7 A2 + s6 s7 A3,  s6=(-1)^(j&1), s7=(-1)^(j>>1)
// — 18 sign-applies + ~26 tree f64 adds instead of 72 serial adds.
// x is prefetched before phase A so the cold HBM latency hides under it.
// a accumulated in f64 (|a| up to ~113 rad); sincos evaluated in f32 after
// exact f64 range reduction f = a/2pi - rint(a/2pi).

namespace {

// Gates regrouped by hi = v>>6 (bits 6,7 of the gate vector):
//   group0 (hi=0): 8 gates, group1 (hi=1/bit6): 1, group2 (hi=2/bit7): 4,
//   group3 (hi=3): 5.
// GLO = v & 0x3F (lane-sign mask), GIX = weight index within the oc row.
constexpr int G0B = 0, G0E = 8;    // hi = 0
constexpr int G1B = 8, G1E = 9;    // hi = 1
constexpr int G2B = 9, G2E = 13;   // hi = 2
constexpr int G3B = 13, G3E = 18;  // hi = 3
constexpr unsigned GLO[18] = {0x08, 0x18, 0x0C, 0x28, 0x0A, 0x3C, 0x1E, 0x0F,
                              0x38,
                              0x00, 0x20, 0x23, 0x11,
                              0x00, 0x01, 0x02, 0x30, 0x07};
constexpr int GIX[18] = {4, 11, 12, 18, 20, 26, 27, 28,
                         25,
                         0, 16, 30, 31,
                         8, 15, 22, 24, 29};

__global__ __launch_bounds__(256) void qconv_kernel(
    const float* __restrict__ x,     // (2, 2, 128, 128) fp32
    const float* __restrict__ wts,   // (4, 4, 8) fp32
    float* __restrict__ out)         // (2, 4, 64, 64) fp32
{
  const int tid  = threadIdx.x;
  const int lane = tid & 63;

  __shared__ float K[4][4];          // [oc][cc,ss,sc,cs]

  // ---- prefetch phase-B inputs first: the cold-HBM latency (~900 cy)
  // overlaps phase A's compute; the pre-barrier vmcnt drain then waits on
  // already-arrived data.
  const int p  = blockIdx.x * 256 + tid;       // 8192 patches
  const int b  = p >> 12;
  const int ph = (p >> 6) & 63;
  const int pw = p & 63;
  const float th0 = x[((b * 2 + 0) * 128 + 2 * ph) * 128 + 2 * pw];
  const float th4 = x[((b * 2 + 1) * 128 + 2 * ph) * 128 + 2 * pw];

  // ---- phase A: coefficients (recomputed identically in every block).
  // wave = oc; lane handles w in {lane, lane+64, lane+128, lane+192}.
  {
    const int oc = __builtin_amdgcn_readfirstlane(tid >> 6);  // SGPR -> s_load
    const float* __restrict__ wo = wts + oc * 32;

    // lane-signed gate angles in f64 (sign flip is exact; applied pre-cvt)
    double t[18];
#pragma unroll
    for (int g = 0; g < 18; ++g) {
      const float v = wo[GIX[g]];
      t[g] = (double)((__popc(lane & GLO[g]) & 1) ? -v : v);
    }
    // grouped partial sums (4 independent chains, tree-shaped)
    const double A0 =
        ((t[0] + t[1]) + (t[2] + t[3])) + ((t[4] + t[5]) + (t[6] + t[7]));
    const double A1 = t[8];
    const double A2 = (t[9] + t[10]) + (t[11] + t[12]);
    const double A3 = ((t[13] + t[14]) + (t[15] + t[16])) + t[17];
    const double P = A0 + A1, M = A0 - A1;
    const double Q = A2 + A3, R = A2 - A3;
    const double a[4] = {P + Q, M + R, P - Q, M - R};  // j = 0..3

    float ca[4], sa[4];
#pragma unroll
    for (int j = 0; j < 4; ++j) {
      // exact-enough range reduction in f64, transcendental in f32
      const double r = a[j] * 0.15915494309189535;   // a / 2pi
      const float  f = (float)(r - rint(r));         // fractional revolutions
      __sincosf(6.283185307179586f * f, &sa[j], &ca[j]);
    }
    // s0 = bit7 of w = j>>1 (lo: j=0,1 / hi: j=2,3); s4 = bit3 of lane.
    const float ca_lo = ca[0] + ca[1], ca_hi = ca[2] + ca[3];
    const float sa_lo = sa[0] + sa[1], sa_hi = sa[2] + sa[3];
    const int s4 = (lane >> 3) & 1;
    float scc = ca_lo + ca_hi;                        // sum ca
    float ssc = sa_hi - sa_lo;                        // sum -eps0*sa
    float scs = s4 ? (sa_lo + sa_hi) : -(sa_lo + sa_hi);  // sum -eps4*sa
    float sss = s4 ? (ca_lo - ca_hi) : (ca_hi - ca_lo);   // sum -eps0*eps4*ca

    // wave-level reduce (64 lanes)
#pragma unroll
    for (int off = 32; off > 0; off >>= 1) {
      scc += __shfl_xor(scc, off, 64);
      sss += __shfl_xor(sss, off, 64);
      ssc += __shfl_xor(ssc, off, 64);
      scs += __shfl_xor(scs, off, 64);
    }
    if (lane == 0) {
      K[oc][0] = scc * (1.0f / 256.0f);
      K[oc][1] = sss * (1.0f / 256.0f);
      K[oc][2] = ssc * (1.0f / 256.0f);
      K[oc][3] = scs * (1.0f / 256.0f);
    }
  }
  __syncthreads();

  // ---- phase B: one thread per patch (inputs already in registers).
  float s0, c0, s4v, c4v;
  __sincosf(th0, &s0, &c0);
  __sincosf(th4, &s4v, &c4v);
  const float cc = c0 * c4v, ss = s0 * s4v, sc = s0 * c4v, cs = c0 * s4v;

  float* __restrict__ o = out + (b * 4 * 64 + ph) * 64 + pw;
#pragma unroll
  for (int oc = 0; oc < 4; ++oc) {
    o[oc * 4096] =
        K[oc][0] * cc + K[oc][1] * ss + K[oc][2] * sc + K[oc][3] * cs;
  }
}

} // namespace

extern "C" void kernel_launch(void* const* d_in, const int* in_sizes, int n_in,
                              void* d_out, int out_size, void* d_ws, size_t ws_size,
                              hipStream_t stream) {
  const float* x   = (const float*)d_in[0];   // 2*2*128*128 = 65536
  const float* wts = (const float*)d_in[1];   // 4*4*8 = 128
  float* out = (float*)d_out;                 // 2*4*64*64 = 32768
  qconv_kernel<<<32, 256, 0, stream>>>(x, wts, out);
}